// Round 1
// baseline (927.248 us; speedup 1.0000x reference)
//
#include <hip/hip_runtime.h>

// Problem constants (from reference)
constexpr int NN = 50000;     // nodes
constexpr int NE = 400000;    // edges
constexpr int NV = 3;         // views
constexpr int DF = 128;       // per-view width
constexpr int F  = 384;       // total feature width (NV*DF)
constexpr int TR = 32;        // node rows per block tile
constexpr int NB = (NN + 255) / 256;  // 196 scan blocks

// ---------------- CSR build (by destination) ----------------

__global__ void k_count(const int* __restrict__ dst, int* __restrict__ deg) {
  int i = blockIdx.x * blockDim.x + threadIdx.x;
  int stride = gridDim.x * blockDim.x;
  for (int e = i; e < NE; e += stride) atomicAdd(&deg[dst[e]], 1);
}

__global__ void k_blocksum(const int* __restrict__ deg, int* __restrict__ bsum) {
  __shared__ int s[4];
  int i = blockIdx.x * 256 + threadIdx.x;
  int v = (i < NN) ? deg[i] : 0;
  for (int o = 32; o > 0; o >>= 1) v += __shfl_down(v, o);  // wave64 reduce
  if ((threadIdx.x & 63) == 0) s[threadIdx.x >> 6] = v;
  __syncthreads();
  if (threadIdx.x == 0) bsum[blockIdx.x] = s[0] + s[1] + s[2] + s[3];
}

__global__ void k_scanb(int* __restrict__ bsum, int nb, int* __restrict__ offs_n) {
  if (threadIdx.x == 0 && blockIdx.x == 0) {
    int run = 0;
    for (int i = 0; i < nb; ++i) { int v = bsum[i]; bsum[i] = run; run += v; }
    *offs_n = run;  // offs[NN] = NE
  }
}

__global__ void k_offsets(const int* __restrict__ deg, const int* __restrict__ bsum,
                          int* __restrict__ offs) {
  __shared__ int s[256];
  int t = threadIdx.x;
  int i = blockIdx.x * 256 + t;
  int v = (i < NN) ? deg[i] : 0;
  s[t] = v;
  __syncthreads();
  for (int o = 1; o < 256; o <<= 1) {     // Hillis-Steele inclusive scan
    int add = (t >= o) ? s[t - o] : 0;
    __syncthreads();
    s[t] += add;
    __syncthreads();
  }
  if (i < NN) offs[i] = bsum[blockIdx.x] + s[t] - v;  // exclusive
}

__global__ void k_scatter(const int* __restrict__ src, const int* __restrict__ dst,
                          const int* __restrict__ offs, int* __restrict__ cnt,
                          int* __restrict__ csr) {
  int i = blockIdx.x * blockDim.x + threadIdx.x;
  int stride = gridDim.x * blockDim.x;
  for (int e = i; e < NE; e += stride) {
    int d = dst[e];
    int pos = offs[d] + atomicAdd(&cnt[d], 1);
    csr[pos] = src[e];
  }
}

// ---------------- Fused aggregate + GEMM(+bias+ReLU) layer ----------------
// out[n, v*DF + h] = relu( bias[h] + sum_d ( sum_{s->n} feat[s, v*DF + d] ) * W[d,h] )

__device__ __forceinline__ float4 relu4(float4 a) {
  a.x = a.x > 0.f ? a.x : 0.f;
  a.y = a.y > 0.f ? a.y : 0.f;
  a.z = a.z > 0.f ? a.z : 0.f;
  a.w = a.w > 0.f ? a.w : 0.f;
  return a;
}

__global__ __launch_bounds__(256, 2)
void k_layer(const float* __restrict__ feat,
             const int* __restrict__ offs, const int* __restrict__ csr,
             const float* __restrict__ Wall, const float* __restrict__ ball,
             int wstride, int bstride, float* __restrict__ out) {
  __shared__ float sW[DF * DF];    // 64 KB: W[d][h]
  __shared__ float sT[TR][DF];     // 16 KB: aggregated tile
  const int t = threadIdx.x;
  const int v = blockIdx.y;
  const float* W = Wall + (size_t)v * wstride;
  const float* bias = ball + (size_t)v * bstride;

  // Stage W into LDS (coalesced float4)
  {
    const float4* W4 = (const float4*)W;
    float4* sW4 = (float4*)sW;
#pragma unroll
    for (int i = 0; i < (DF * DF / 4) / 256; ++i)  // 16 iters
      sW4[t + i * 256] = W4[t + i * 256];
  }

  // Phase A: aggregate. One wave per node-row; lane holds float2 (128 cols / 64 lanes).
  const int wave = t >> 6, lane = t & 63;
  const int row0 = blockIdx.x * TR;
#pragma unroll
  for (int rr = 0; rr < TR / 4; ++rr) {
    int r = rr * 4 + wave;
    int node = row0 + r;
    float ax = 0.f, ay = 0.f;
    if (node < NN) {
      int e0 = offs[node], e1 = offs[node + 1];
      for (int e = e0; e < e1; ++e) {
        int s = csr[e];
        const float2 x = *(const float2*)(feat + (size_t)s * F + v * DF + lane * 2);
        ax += x.x; ay += x.y;
      }
    }
    sT[r][lane * 2]     = ax;
    sT[r][lane * 2 + 1] = ay;
  }
  __syncthreads();

  // Phase B: GEMM. Thread tile = 4 rows x 4 cols. 32 col-groups x 8 row-groups.
  const int cg = t & 31, rg = t >> 5;
  const int c = cg * 4;
  const float4 b4 = *(const float4*)(bias + c);
  float4 a0 = b4, a1 = b4, a2 = b4, a3 = b4;
#pragma unroll 8
  for (int d = 0; d < DF; ++d) {
    float4 w = *(const float4*)(&sW[d * DF + c]);
    float x0 = sT[rg * 4 + 0][d];
    float x1 = sT[rg * 4 + 1][d];
    float x2 = sT[rg * 4 + 2][d];
    float x3 = sT[rg * 4 + 3][d];
    a0.x = fmaf(x0, w.x, a0.x); a0.y = fmaf(x0, w.y, a0.y);
    a0.z = fmaf(x0, w.z, a0.z); a0.w = fmaf(x0, w.w, a0.w);
    a1.x = fmaf(x1, w.x, a1.x); a1.y = fmaf(x1, w.y, a1.y);
    a1.z = fmaf(x1, w.z, a1.z); a1.w = fmaf(x1, w.w, a1.w);
    a2.x = fmaf(x2, w.x, a2.x); a2.y = fmaf(x2, w.y, a2.y);
    a2.z = fmaf(x2, w.z, a2.z); a2.w = fmaf(x2, w.w, a2.w);
    a3.x = fmaf(x3, w.x, a3.x); a3.y = fmaf(x3, w.y, a3.y);
    a3.z = fmaf(x3, w.z, a3.z); a3.w = fmaf(x3, w.w, a3.w);
  }

  const int nodeb = row0 + rg * 4;
  if (nodeb + 0 < NN) *(float4*)(out + (size_t)(nodeb + 0) * F + v * DF + c) = relu4(a0);
  if (nodeb + 1 < NN) *(float4*)(out + (size_t)(nodeb + 1) * F + v * DF + c) = relu4(a1);
  if (nodeb + 2 < NN) *(float4*)(out + (size_t)(nodeb + 2) * F + v * DF + c) = relu4(a2);
  if (nodeb + 3 < NN) *(float4*)(out + (size_t)(nodeb + 3) * F + v * DF + c) = relu4(a3);
}

// ---------------- launch ----------------

static inline size_t align_up(size_t x, size_t a) { return (x + a - 1) & ~(a - 1); }

extern "C" void kernel_launch(void* const* d_in, const int* in_sizes, int n_in,
                              void* d_out, int out_size, void* d_ws, size_t ws_size,
                              hipStream_t stream) {
  const float* h   = (const float*)d_in[0];
  const int*   src = (const int*)d_in[1];
  const int*   dst = (const int*)d_in[2];
  const float* W1  = (const float*)d_in[3];
  const float* b1  = (const float*)d_in[4];
  const float* W2  = (const float*)d_in[5];
  const float* b2  = (const float*)d_in[6];
  float* out = (float*)d_out;

  // Workspace layout
  char* ws = (char*)d_ws;
  size_t o = 0;
  int* deg  = (int*)(ws + o); o = align_up(o + (size_t)NN * 4, 1024);        // also reused as scatter cursor
  int* offs = (int*)(ws + o); o = align_up(o + (size_t)(NN + 1) * 4, 1024);
  int* bsum = (int*)(ws + o); o = align_up(o + 1024, 1024);
  int* csr  = (int*)(ws + o); o = align_up(o + (size_t)NE * 4, 1024);
  float* ybuf = (float*)(ws + o); o += (size_t)NN * F * 4;
  (void)ws_size; (void)n_in; (void)in_sizes; (void)out_size;

  // CSR build
  hipMemsetAsync(deg, 0, (size_t)NN * 4, stream);
  k_count<<<1024, 256, 0, stream>>>(dst, deg);
  k_blocksum<<<NB, 256, 0, stream>>>(deg, bsum);
  k_scanb<<<1, 64, 0, stream>>>(bsum, NB, offs + NN);
  k_offsets<<<NB, 256, 0, stream>>>(deg, bsum, offs);
  hipMemsetAsync(deg, 0, (size_t)NN * 4, stream);  // reuse as per-node cursor
  k_scatter<<<1024, 256, 0, stream>>>(src, dst, offs, deg, csr);

  // Two fused layers: layer1 per-view W1/b1, layer2 shared W2/b2
  dim3 grid((NN + TR - 1) / TR, NV);
  k_layer<<<grid, 256, 0, stream>>>(h,    offs, csr, W1, b1, DF * DF, DF, ybuf);
  k_layer<<<grid, 256, 0, stream>>>(ybuf, offs, csr, W2, b2, 0,       0,  out);
}

// Round 2
// 360.764 us; speedup vs baseline: 2.5702x; 2.5702x over previous
//
#include <hip/hip_runtime.h>

// Problem constants (from reference)
constexpr int NN = 50000;     // nodes
constexpr int NE = 400000;    // edges
constexpr int NV = 3;         // views
constexpr int DF = 128;       // per-view width
constexpr int F  = 384;       // total feature width (NV*DF)
constexpr int TR = 32;        // node rows per block tile
constexpr int NB = (NN + 255) / 256;  // 196 scan blocks

// ---------------- CSR build (by destination) ----------------

__global__ void k_count(const int* __restrict__ dst, int* __restrict__ deg) {
  int i = blockIdx.x * blockDim.x + threadIdx.x;
  int stride = gridDim.x * blockDim.x;
  for (int e = i; e < NE; e += stride) atomicAdd(&deg[dst[e]], 1);
}

__global__ void k_blocksum(const int* __restrict__ deg, int* __restrict__ bsum) {
  __shared__ int s[4];
  int i = blockIdx.x * 256 + threadIdx.x;
  int v = (i < NN) ? deg[i] : 0;
  for (int o = 32; o > 0; o >>= 1) v += __shfl_down(v, o);  // wave64 reduce
  if ((threadIdx.x & 63) == 0) s[threadIdx.x >> 6] = v;
  __syncthreads();
  if (threadIdx.x == 0) bsum[blockIdx.x] = s[0] + s[1] + s[2] + s[3];
}

__global__ void k_scanb(int* __restrict__ bsum, int nb, int* __restrict__ offs_n) {
  if (threadIdx.x == 0 && blockIdx.x == 0) {
    int run = 0;
    for (int i = 0; i < nb; ++i) { int v = bsum[i]; bsum[i] = run; run += v; }
    *offs_n = run;  // offs[NN] = NE
  }
}

__global__ void k_offsets(const int* __restrict__ deg, const int* __restrict__ bsum,
                          int* __restrict__ offs) {
  __shared__ int s[256];
  int t = threadIdx.x;
  int i = blockIdx.x * 256 + t;
  int v = (i < NN) ? deg[i] : 0;
  s[t] = v;
  __syncthreads();
  for (int o = 1; o < 256; o <<= 1) {     // Hillis-Steele inclusive scan
    int add = (t >= o) ? s[t - o] : 0;
    __syncthreads();
    s[t] += add;
    __syncthreads();
  }
  if (i < NN) offs[i] = bsum[blockIdx.x] + s[t] - v;  // exclusive
}

__global__ void k_scatter(const int* __restrict__ src, const int* __restrict__ dst,
                          const int* __restrict__ offs, int* __restrict__ cnt,
                          int* __restrict__ csr) {
  int i = blockIdx.x * blockDim.x + threadIdx.x;
  int stride = gridDim.x * blockDim.x;
  for (int e = i; e < NE; e += stride) {
    int d = dst[e];
    int pos = offs[d] + atomicAdd(&cnt[d], 1);
    csr[pos] = src[e];
  }
}

// ---------------- Fused aggregate + GEMM(+bias+ReLU) layer ----------------
// out[n, v*DF + h] = relu( bias[h] + sum_d ( sum_{s->n} feat[s, v*DF + d] ) * W[d,h] )

__device__ __forceinline__ float4 relu4(float4 a) {
  a.x = a.x > 0.f ? a.x : 0.f;
  a.y = a.y > 0.f ? a.y : 0.f;
  a.z = a.z > 0.f ? a.z : 0.f;
  a.w = a.w > 0.f ? a.w : 0.f;
  return a;
}

__global__ __launch_bounds__(256, 4)
void k_layer(const float* __restrict__ feat,
             const int* __restrict__ offs, const int* __restrict__ csr,
             const float* __restrict__ Wall, const float* __restrict__ ball,
             int wstride, int bstride, float* __restrict__ out) {
  __shared__ float sT[TR][DF];     // 16 KB: aggregated tile
  const int t = threadIdx.x;
  const int v = blockIdx.y;
  const float* __restrict__ W = Wall + (size_t)v * wstride;
  const float* __restrict__ bias = ball + (size_t)v * bstride;

  // Phase A: aggregate. One wave per node-row; lane holds float2 (128 cols / 64 lanes).
  // Batch-load up to 64 edge indices coalesced, broadcast via readlane (SGPR base),
  // issue 4 independent 512B gathers per step -> multiple loads in flight.
  const int wave = t >> 6, lane = t & 63;
  const int row0 = blockIdx.x * TR;
  const int vcol = v * DF + lane * 2;

#pragma unroll
  for (int rr = 0; rr < TR / 4; ++rr) {
    int r = rr * 4 + wave;
    int node = row0 + r;
    float ax = 0.f, ay = 0.f;
    if (node < NN) {
      int e0 = offs[node], e1 = offs[node + 1];
      int e = e0;
      while (e < e1) {                    // wave-uniform loop
        int n = e1 - e; if (n > 64) n = 64;
        int ce = e + lane; if (ce > e1 - 1) ce = e1 - 1;   // clamped coalesced index load
        int idx = csr[ce];
        int j = 0;
        for (; j + 4 <= n; j += 4) {      // 4 independent gathers in flight
          int s0 = __builtin_amdgcn_readlane(idx, j);
          int s1 = __builtin_amdgcn_readlane(idx, j + 1);
          int s2 = __builtin_amdgcn_readlane(idx, j + 2);
          int s3 = __builtin_amdgcn_readlane(idx, j + 3);
          float2 x0 = *(const float2*)(feat + (size_t)s0 * F + vcol);
          float2 x1 = *(const float2*)(feat + (size_t)s1 * F + vcol);
          float2 x2 = *(const float2*)(feat + (size_t)s2 * F + vcol);
          float2 x3 = *(const float2*)(feat + (size_t)s3 * F + vcol);
          ax += x0.x; ay += x0.y;
          ax += x1.x; ay += x1.y;
          ax += x2.x; ay += x2.y;
          ax += x3.x; ay += x3.y;
        }
        for (; j < n; ++j) {
          int s0 = __builtin_amdgcn_readlane(idx, j);
          float2 x0 = *(const float2*)(feat + (size_t)s0 * F + vcol);
          ax += x0.x; ay += x0.y;
        }
        e += n;
      }
    }
    sT[r][lane * 2]     = ax;
    sT[r][lane * 2 + 1] = ay;
  }
  __syncthreads();

  // Phase B: GEMM. Thread tile = 4 rows x 4 cols. W read from global (L1/L2-resident,
  // wave-broadcast row access) -- no LDS stage, keeps occupancy at 4 blocks/CU.
  const int cg = t & 31, rg = t >> 5;
  const int c = cg * 4;
  const float4 b4 = *(const float4*)(bias + c);
  float4 a0 = b4, a1 = b4, a2 = b4, a3 = b4;
  const float4* __restrict__ W4 = (const float4*)W;
#pragma unroll 8
  for (int d = 0; d < DF; ++d) {
    float4 w = W4[d * (DF / 4) + cg];
    float x0 = sT[rg * 4 + 0][d];
    float x1 = sT[rg * 4 + 1][d];
    float x2 = sT[rg * 4 + 2][d];
    float x3 = sT[rg * 4 + 3][d];
    a0.x = fmaf(x0, w.x, a0.x); a0.y = fmaf(x0, w.y, a0.y);
    a0.z = fmaf(x0, w.z, a0.z); a0.w = fmaf(x0, w.w, a0.w);
    a1.x = fmaf(x1, w.x, a1.x); a1.y = fmaf(x1, w.y, a1.y);
    a1.z = fmaf(x1, w.z, a1.z); a1.w = fmaf(x1, w.w, a1.w);
    a2.x = fmaf(x2, w.x, a2.x); a2.y = fmaf(x2, w.y, a2.y);
    a2.z = fmaf(x2, w.z, a2.z); a2.w = fmaf(x2, w.w, a2.w);
    a3.x = fmaf(x3, w.x, a3.x); a3.y = fmaf(x3, w.y, a3.y);
    a3.z = fmaf(x3, w.z, a3.z); a3.w = fmaf(x3, w.w, a3.w);
  }

  const int nodeb = row0 + rg * 4;
  if (nodeb + 0 < NN) *(float4*)(out + (size_t)(nodeb + 0) * F + v * DF + c) = relu4(a0);
  if (nodeb + 1 < NN) *(float4*)(out + (size_t)(nodeb + 1) * F + v * DF + c) = relu4(a1);
  if (nodeb + 2 < NN) *(float4*)(out + (size_t)(nodeb + 2) * F + v * DF + c) = relu4(a2);
  if (nodeb + 3 < NN) *(float4*)(out + (size_t)(nodeb + 3) * F + v * DF + c) = relu4(a3);
}

// ---------------- launch ----------------

static inline size_t align_up(size_t x, size_t a) { return (x + a - 1) & ~(a - 1); }

extern "C" void kernel_launch(void* const* d_in, const int* in_sizes, int n_in,
                              void* d_out, int out_size, void* d_ws, size_t ws_size,
                              hipStream_t stream) {
  const float* h   = (const float*)d_in[0];
  const int*   src = (const int*)d_in[1];
  const int*   dst = (const int*)d_in[2];
  const float* W1  = (const float*)d_in[3];
  const float* b1  = (const float*)d_in[4];
  const float* W2  = (const float*)d_in[5];
  const float* b2  = (const float*)d_in[6];
  float* out = (float*)d_out;

  // Workspace layout
  char* ws = (char*)d_ws;
  size_t o = 0;
  int* deg  = (int*)(ws + o); o = align_up(o + (size_t)NN * 4, 1024);        // also reused as scatter cursor
  int* offs = (int*)(ws + o); o = align_up(o + (size_t)(NN + 1) * 4, 1024);
  int* bsum = (int*)(ws + o); o = align_up(o + 1024, 1024);
  int* csr  = (int*)(ws + o); o = align_up(o + (size_t)NE * 4, 1024);
  float* ybuf = (float*)(ws + o); o += (size_t)NN * F * 4;
  (void)ws_size; (void)n_in; (void)in_sizes; (void)out_size;

  // CSR build
  hipMemsetAsync(deg, 0, (size_t)NN * 4, stream);
  k_count<<<1024, 256, 0, stream>>>(dst, deg);
  k_blocksum<<<NB, 256, 0, stream>>>(deg, bsum);
  k_scanb<<<1, 64, 0, stream>>>(bsum, NB, offs + NN);
  k_offsets<<<NB, 256, 0, stream>>>(deg, bsum, offs);
  hipMemsetAsync(deg, 0, (size_t)NN * 4, stream);  // reuse as per-node cursor
  k_scatter<<<1024, 256, 0, stream>>>(src, dst, offs, deg, csr);

  // Two fused layers: layer1 per-view W1/b1, layer2 shared W2/b2
  dim3 grid((NN + TR - 1) / TR, NV);
  k_layer<<<grid, 256, 0, stream>>>(h,    offs, csr, W1, b1, DF * DF, DF, ybuf);
  k_layer<<<grid, 256, 0, stream>>>(ybuf, offs, csr, W2, b2, 0,       0,  out);
}